// Round 1
// 96.773 us; speedup vs baseline: 1.1163x; 1.1163x over previous
//
#include <hip/hip_runtime.h>
#include <hip/hip_fp16.h>
#include <math.h>

#define NN 20000
#define EE 320000
#define CIN 16
#define COUT 16
#define R2C 0.25f
#define MAXDEG 64

// workspace layout:
//   cnt_all : int[NN]            @ 0
//   slotc   : int[NN]            @ 81920
//   filtH   : half[16384]        @ 163840   (32 KB, transposed [cell][ci_hi][o][ci_lo8])
//   featH   : half[NN*16]        @ 196608   (640 KB)
//   conv    : float[NN*MAXDEG*16]@ 836608   (81.92 MB, fp32 slots)
#define SLOTC_OFF 81920
#define FILTH_OFF 163840
#define FEATH_OFF 196608
#define CONV_OFF  836608

typedef _Float16 h2 __attribute__((ext_vector_type(2)));

#if defined(__has_builtin)
# if __has_builtin(__builtin_amdgcn_fdot2)
#  define HAS_FDOT2 1
# endif
#endif
#ifndef HAS_FDOT2
# define HAS_FDOT2 0
#endif

__device__ __forceinline__ h2 as_h2(unsigned int x) {
    union { unsigned int u; h2 h; } v; v.u = x; return v.h;
}

// ---------------- prep: zero counters, cast feat to fp16, transpose filters to fp16 ----------------
// filt src linear: cell*256 + ci*16 + o  (cell = i*16+j*4+k)
// filtH dst: [cell][ci>>3][o][ci&7]  -> granule (16B) = cell*32 + (ci>>3)*16 + o
__global__ __launch_bounds__(256) void k_prep(const float* __restrict__ feat,
                                              const float* __restrict__ filt,
                                              __half* __restrict__ featH,
                                              __half* __restrict__ filtH,
                                              int* __restrict__ cnt_all,
                                              int* __restrict__ slotc) {
    int t = blockIdx.x * 256 + threadIdx.x;
    if (t < NN) { cnt_all[t] = 0; slotc[t] = 0; }
    if (t < 16384) {
        int cell = t >> 8, rem = t & 255, ci = rem >> 4, oo = rem & 15;
        int d = cell * 256 + (ci >> 3) * 128 + oo * 8 + (ci & 7);
        filtH[d] = __float2half(filt[t]);
    }
    if (t < NN * 16) featH[t] = __float2half(feat[t]);
}

// ---------------- fused edge kernel: geometry (1 lane/edge) + compaction + LDS-filter conv ----------------
// grid = EE/(4 waves * 64 lanes) = 1250 blocks exactly; e < EE by construction.
__global__ __launch_bounds__(256) void k_edge(const float* __restrict__ pos,
                                              const int* __restrict__ ei,
                                              const __half* __restrict__ featH,
                                              const uint4* __restrict__ filtH4,
                                              float* __restrict__ conv,
                                              int* __restrict__ cnt_all,
                                              int* __restrict__ slotc) {
    __shared__ uint4 sf[2048];   // 32 KiB fp16 filters
    #pragma unroll
    for (int r = 0; r < 8; ++r)
        sf[r * 256 + threadIdx.x] = filtH4[r * 256 + threadIdx.x];
    __syncthreads();

    int lane = threadIdx.x & 63;
    int gid  = lane >> 4;        // 16-lane group id within wave (0..3)
    int o    = lane & 15;        // output channel owned in compute phase
    int e = (blockIdx.x * 4 + (threadIdx.x >> 6)) * 64 + lane;

    int row = ei[e];
    int col = ei[EE + e];
    atomicAdd(&cnt_all[row], 1);   // mean divisor counts ALL edges

    float rx = pos[col*3+0] - pos[row*3+0];
    float ry = pos[col*3+1] - pos[row*3+1];
    float rz = pos[col*3+2] - pos[row*3+2];
    float d2 = rx*rx + ry*ry + rz*rz;
    bool valid = d2 < R2C;

    float win = 0.f, ad = 0.f, bd = 0.f, cd = 0.f;
    int colidx = 0, rowslot = 0;
    if (valid) {
        float u = 1.0f - d2 * 4.0f;           // 1 - d2/R^2
        win = u * u * u;
        float nr = sqrtf(d2);
        float s  = tanhf(nr) / (nr + 1e-8f);
        float gx = (rx * s + 1.0f) * 1.5f;    // c-axis (k)
        float gy = (ry * s + 1.0f) * 1.5f;    // b-axis (j)
        float gz = (rz * s + 1.0f) * 1.5f;    // a-axis (i)
        float af = floorf(gz), bf = floorf(gy), cf = floorf(gx);
        // gc in (0.75, 2.25) -> floor in {0,1,2}; clamps are safety only
        int ia0 = min(max((int)af, 0), 2);
        int jb0 = min(max((int)bf, 0), 2);
        int kc0 = min(max((int)cf, 0), 2);
        ad = gz - af; bd = gy - bf; cd = gx - cf;
        colidx = col | (ia0 << 20) | (jb0 << 24) | (kc0 << 28);
        int slot = atomicAdd(&slotc[row], 1);
        rowslot = row | (min(slot, MAXDEG) << 16);
    }

    unsigned long long bal = __ballot(valid);
    int nv = __popcll(bal);
    unsigned long long m0 = bal;
    unsigned long long m1 = m0 & (m0 - 1);
    unsigned long long m2 = m1 & (m1 - 1);
    unsigned long long m3 = m2 & (m2 - 1);

    for (int k = 0; k < nv; k += 4) {
        unsigned long long mg = (gid == 0) ? m0 : (gid == 1) ? m1 : (gid == 2) ? m2 : m3;
        bool active = (k + gid) < nv;
        int src = active ? (int)__builtin_ctzll(mg) : 0;

        // all 64 lanes shuffle (src lanes always hold defined values)
        float win_s = __shfl(win, src, 64);
        float ad_s  = __shfl(ad,  src, 64);
        float bd_s  = __shfl(bd,  src, 64);
        float cd_s  = __shfl(cd,  src, 64);
        int   ci_s  = __shfl(colidx,  src, 64);
        int   rs_s  = __shfl(rowslot, src, 64);

        // advance: clear 4 more low bits
        m0 = m3 & (m3 - 1);
        m1 = m0 & (m0 - 1);
        m2 = m1 & (m1 - 1);
        m3 = m2 & (m2 - 1);

        if (active) {
            int col_s  = ci_s & 0xFFFFF;
            int ia0 = (ci_s >> 20) & 3, jb0 = (ci_s >> 24) & 3, kc0 = (ci_s >> 28) & 3;
            int row_s  = rs_s & 0xFFFF;
            int slot_s = rs_s >> 16;

            const uint4* fb = (const uint4*)(featH + (size_t)col_s * 16);
            uint4 fA = fb[0], fB = fb[1];

            float va0 = (1.f - ad_s) * win_s, va1 = ad_s * win_s;
            float vb0 = 1.f - bd_s, vb1 = bd_s;
            float vc0 = 1.f - cd_s, vc1 = cd_s;
            float p00 = va0*vb0, p01 = va0*vb1, p10 = va1*vb0, p11 = va1*vb1;
            float w8[8] = { p00*vc0, p00*vc1, p01*vc0, p01*vc1,
                            p10*vc0, p10*vc1, p11*vc0, p11*vc1 };

            // base granule index of corner (ia0,jb0,kc0), + per-lane o
            int bi = ((ia0 * 16 + jb0 * 4 + kc0) << 5) + o;
            // relative cells {(0,0,0),(0,0,1),(0,1,0),(0,1,1),(1,0,0),(1,0,1),(1,1,0),(1,1,1)} * 32 granules
            const int cofs[8] = {0, 32, 128, 160, 512, 544, 640, 672};

            float acc = 0.f;
#if HAS_FDOT2
            h2 ft0 = as_h2(fA.x), ft1 = as_h2(fA.y), ft2 = as_h2(fA.z), ft3 = as_h2(fA.w);
            h2 ft4 = as_h2(fB.x), ft5 = as_h2(fB.y), ft6 = as_h2(fB.z), ft7 = as_h2(fB.w);
            #pragma unroll
            for (int c = 0; c < 8; ++c) {
                uint4 g0 = sf[bi + cofs[c]];
                uint4 g1 = sf[bi + cofs[c] + 16];
                float d = 0.f;
                d = __builtin_amdgcn_fdot2(as_h2(g0.x), ft0, d, false);
                d = __builtin_amdgcn_fdot2(as_h2(g0.y), ft1, d, false);
                d = __builtin_amdgcn_fdot2(as_h2(g0.z), ft2, d, false);
                d = __builtin_amdgcn_fdot2(as_h2(g0.w), ft3, d, false);
                d = __builtin_amdgcn_fdot2(as_h2(g1.x), ft4, d, false);
                d = __builtin_amdgcn_fdot2(as_h2(g1.y), ft5, d, false);
                d = __builtin_amdgcn_fdot2(as_h2(g1.z), ft6, d, false);
                d = __builtin_amdgcn_fdot2(as_h2(g1.w), ft7, d, false);
                acc = fmaf(w8[c], d, acc);
            }
#else
            float ftf[16];
            { h2 t;
              t = as_h2(fA.x); ftf[0]=(float)t.x;  ftf[1]=(float)t.y;
              t = as_h2(fA.y); ftf[2]=(float)t.x;  ftf[3]=(float)t.y;
              t = as_h2(fA.z); ftf[4]=(float)t.x;  ftf[5]=(float)t.y;
              t = as_h2(fA.w); ftf[6]=(float)t.x;  ftf[7]=(float)t.y;
              t = as_h2(fB.x); ftf[8]=(float)t.x;  ftf[9]=(float)t.y;
              t = as_h2(fB.y); ftf[10]=(float)t.x; ftf[11]=(float)t.y;
              t = as_h2(fB.z); ftf[12]=(float)t.x; ftf[13]=(float)t.y;
              t = as_h2(fB.w); ftf[14]=(float)t.x; ftf[15]=(float)t.y; }
            #pragma unroll
            for (int c = 0; c < 8; ++c) {
                uint4 g0 = sf[bi + cofs[c]];
                uint4 g1 = sf[bi + cofs[c] + 16];
                float d = 0.f;
                h2 t;
                t = as_h2(g0.x); d = fmaf((float)t.x, ftf[0],  d); d = fmaf((float)t.y, ftf[1],  d);
                t = as_h2(g0.y); d = fmaf((float)t.x, ftf[2],  d); d = fmaf((float)t.y, ftf[3],  d);
                t = as_h2(g0.z); d = fmaf((float)t.x, ftf[4],  d); d = fmaf((float)t.y, ftf[5],  d);
                t = as_h2(g0.w); d = fmaf((float)t.x, ftf[6],  d); d = fmaf((float)t.y, ftf[7],  d);
                t = as_h2(g1.x); d = fmaf((float)t.x, ftf[8],  d); d = fmaf((float)t.y, ftf[9],  d);
                t = as_h2(g1.y); d = fmaf((float)t.x, ftf[10], d); d = fmaf((float)t.y, ftf[11], d);
                t = as_h2(g1.z); d = fmaf((float)t.x, ftf[12], d); d = fmaf((float)t.y, ftf[13], d);
                t = as_h2(g1.w); d = fmaf((float)t.x, ftf[14], d); d = fmaf((float)t.y, ftf[15], d);
                acc = fmaf(w8[c], d, acc);
            }
#endif
            if (slot_s < MAXDEG)
                conv[((size_t)row_s * MAXDEG + slot_s) * 16 + o] = acc;
        }
    }
}

// ---------------- gather: per-node slot-sum + mean (fp32 slots) ----------------
__global__ __launch_bounds__(256) void k_gather(const float* __restrict__ conv,
                                                const int* __restrict__ cnt_all,
                                                const int* __restrict__ slotc,
                                                float* __restrict__ out) {
    int t = blockIdx.x * 256 + threadIdx.x;
    int n = t >> 3;
    int h = t & 7;
    if (n >= NN) return;
    int deg = min(slotc[n], MAXDEG);
    int ca  = cnt_all[n];
    float2 acc = make_float2(0.f, 0.f);
    const float2* base = (const float2*)(conv + (size_t)n * MAXDEG * 16) + h;
    for (int s = 0; s < deg; ++s) {
        float2 p = base[(size_t)s * 8];
        acc.x += p.x;
        acc.y += p.y;
    }
    float inv = 1.0f / (float)max(ca, 1);
    *(float2*)(out + (size_t)n * 16 + h * 2) = make_float2(acc.x * inv, acc.y * inv);
}

// ---------------- fallback-path zero (out + counters) ----------------
__global__ __launch_bounds__(256) void k_zero(float* __restrict__ out, int* __restrict__ cnt) {
    int i = blockIdx.x * 256 + threadIdx.x;
    if (i < NN * COUT) out[i] = 0.0f;
    if (i < NN) cnt[i] = 0;
}

// ---------------- geometry helper (fallback path) ----------------
__device__ __forceinline__ bool edge_geom(const float* __restrict__ pos, int row, int col,
                                          float& win,
                                          int ia[2], int jb[2], int kc[2],
                                          float wa[2], float wb[2], float wc[2]) {
    float rx = pos[col*3+0] - pos[row*3+0];
    float ry = pos[col*3+1] - pos[row*3+1];
    float rz = pos[col*3+2] - pos[row*3+2];
    float d2 = rx*rx + ry*ry + rz*rz;
    if (!(d2 < R2C)) return false;
    float u = 1.0f - d2 / R2C;
    win = u * u * u;
    float nr = sqrtf(d2);
    float s  = tanhf(nr) / (nr + 1e-8f);
    float gx = (rx * s + 1.0f) * 1.5f;
    float gy = (ry * s + 1.0f) * 1.5f;
    float gz = (rz * s + 1.0f) * 1.5f;
    float af = floorf(gz), bf = floorf(gy), cf = floorf(gx);
    int ia0 = min(max((int)af, 0), 3);
    int ib0 = min(max((int)bf, 0), 3);
    int ic0 = min(max((int)cf, 0), 3);
    ia[0] = ia0; ia[1] = min(ia0 + 1, 3);
    jb[0] = ib0; jb[1] = min(ib0 + 1, 3);
    kc[0] = ic0; kc[1] = min(ic0 + 1, 3);
    float ad = gz - af, bd = gy - bf, cd = gx - cf;
    wa[0] = 1.0f - ad; wa[1] = ad;
    wb[0] = 1.0f - bd; wb[1] = bd;
    wc[0] = 1.0f - cd; wc[1] = cd;
    return true;
}

// ---------------- fallback: direct edge kernel, filters from global ----------------
__global__ __launch_bounds__(256) void k_edge_direct(const float* __restrict__ pos,
                                                     const float* __restrict__ feat,
                                                     const float* __restrict__ filt,
                                                     const int* __restrict__ ei,
                                                     float* __restrict__ out,
                                                     int* __restrict__ cnt) {
    int e = blockIdx.x * 256 + threadIdx.x;
    if (e >= EE) return;
    int row = ei[e];
    int col = ei[EE + e];
    atomicAdd(&cnt[row], 1);

    float win;
    int ia[2], jb[2], kc[2];
    float wa[2], wb[2], wc[2];
    if (!edge_geom(pos, row, col, win, ia, jb, kc, wa, wb, wc)) return;

    float fv[16];
    const float4* fp = (const float4*)(feat + (size_t)col * 16);
    float4 f0 = fp[0], f1 = fp[1], f2 = fp[2], f3 = fp[3];
    fv[0]=f0.x; fv[1]=f0.y; fv[2]=f0.z; fv[3]=f0.w;
    fv[4]=f1.x; fv[5]=f1.y; fv[6]=f1.z; fv[7]=f1.w;
    fv[8]=f2.x; fv[9]=f2.y; fv[10]=f2.z; fv[11]=f2.w;
    fv[12]=f3.x; fv[13]=f3.y; fv[14]=f3.z; fv[15]=f3.w;

    float4 a0 = make_float4(0.f,0.f,0.f,0.f);
    float4 a1 = a0, a2 = a0, a3 = a0;
    for (int da = 0; da < 2; ++da)
    for (int db = 0; db < 2; ++db)
    for (int dc = 0; dc < 2; ++dc) {
        float w = wa[da] * wb[db] * wc[dc] * win;
        const float* fb = filt + (size_t)(ia[da]*16 + jb[db]*4 + kc[dc]) * 256;
        #pragma unroll
        for (int ci = 0; ci < 16; ++ci) {
            float c = w * fv[ci];
            const float4* r4 = (const float4*)(fb + ci * 16);
            float4 w0 = r4[0], w1 = r4[1], w2 = r4[2], w3 = r4[3];
            a0.x = fmaf(c, w0.x, a0.x); a0.y = fmaf(c, w0.y, a0.y);
            a0.z = fmaf(c, w0.z, a0.z); a0.w = fmaf(c, w0.w, a0.w);
            a1.x = fmaf(c, w1.x, a1.x); a1.y = fmaf(c, w1.y, a1.y);
            a1.z = fmaf(c, w1.z, a1.z); a1.w = fmaf(c, w1.w, a1.w);
            a2.x = fmaf(c, w2.x, a2.x); a2.y = fmaf(c, w2.y, a2.y);
            a2.z = fmaf(c, w2.z, a2.z); a2.w = fmaf(c, w2.w, a2.w);
            a3.x = fmaf(c, w3.x, a3.x); a3.y = fmaf(c, w3.y, a3.y);
            a3.z = fmaf(c, w3.z, a3.z); a3.w = fmaf(c, w3.w, a3.w);
        }
    }
    float* op = out + (size_t)row * 16;
    atomicAdd(op+0,  a0.x); atomicAdd(op+1,  a0.y); atomicAdd(op+2,  a0.z); atomicAdd(op+3,  a0.w);
    atomicAdd(op+4,  a1.x); atomicAdd(op+5,  a1.y); atomicAdd(op+6,  a1.z); atomicAdd(op+7,  a1.w);
    atomicAdd(op+8,  a2.x); atomicAdd(op+9,  a2.y); atomicAdd(op+10, a2.z); atomicAdd(op+11, a2.w);
    atomicAdd(op+12, a3.x); atomicAdd(op+13, a3.y); atomicAdd(op+14, a3.z); atomicAdd(op+15, a3.w);
}

// ---------------- fallback divide ----------------
__global__ __launch_bounds__(256) void k_div(float* __restrict__ out, const int* __restrict__ cnt) {
    int i = blockIdx.x * 256 + threadIdx.x;
    if (i >= NN * COUT) return;
    int c = cnt[i >> 4];
    float denom = (c > 1) ? (float)c : 1.0f;
    out[i] = out[i] / denom;
}

extern "C" void kernel_launch(void* const* d_in, const int* in_sizes, int n_in,
                              void* d_out, int out_size, void* d_ws, size_t ws_size,
                              hipStream_t stream) {
    const float* pos  = (const float*)d_in[0];
    const float* feat = (const float*)d_in[1];
    const float* filt = (const float*)d_in[2];
    const int*   ei   = (const int*)d_in[3];
    float* out = (float*)d_out;

    int*    cnt_all = (int*)d_ws;
    int*    slotc   = (int*)((char*)d_ws + SLOTC_OFF);
    __half* filtH   = (__half*)((char*)d_ws + FILTH_OFF);
    __half* featH   = (__half*)((char*)d_ws + FEATH_OFF);
    float*  conv    = (float*)((char*)d_ws + CONV_OFF);

    size_t need = (size_t)CONV_OFF + (size_t)NN * MAXDEG * 16 * sizeof(float);

    if (ws_size >= need) {
        k_prep<<<1250, 256, 0, stream>>>(feat, filt, featH, filtH, cnt_all, slotc);
        k_edge<<<1250, 256, 0, stream>>>(pos, ei, featH, (const uint4*)filtH, conv, cnt_all, slotc);
        k_gather<<<(NN * 8 + 255) / 256, 256, 0, stream>>>(conv, cnt_all, slotc, out);
    } else {
        k_zero<<<(NN * COUT + 255) / 256, 256, 0, stream>>>(out, cnt_all);
        k_edge_direct<<<(EE + 255) / 256, 256, 0, stream>>>(pos, feat, filt, ei, out, cnt_all);
        k_div<<<(NN * COUT + 255) / 256, 256, 0, stream>>>(out, cnt_all);
    }
}

// Round 2
// 94.337 us; speedup vs baseline: 1.1451x; 1.0258x over previous
//
#include <hip/hip_runtime.h>
#include <hip/hip_fp16.h>
#include <math.h>

#define NN 20000
#define EE 320000
#define CIN 16
#define COUT 16
#define R2C 0.25f
#define MAXDEG 32

// workspace layout:
//   cnts : int[NN] @ 0          packed: low16 = total incident edges, high16 = valid-slot counter
//   conv : float[NN*MAXDEG*16] @ 81920   (40.96 MB, fp32 slots)
#define CONV_OFF 81920

typedef _Float16 h2 __attribute__((ext_vector_type(2)));

#if defined(__has_builtin)
# if __has_builtin(__builtin_amdgcn_fdot2)
#  define HAS_FDOT2 1
# endif
#endif
#ifndef HAS_FDOT2
# define HAS_FDOT2 0
#endif

__device__ __forceinline__ h2 as_h2(unsigned int x) {
    union { unsigned int u; h2 h; } v; v.u = x; return v.h;
}
__device__ __forceinline__ h2 pk(float a, float b) {
    h2 r; r.x = (_Float16)a; r.y = (_Float16)b; return r;
}

// ---------------- zero packed counters ----------------
__global__ __launch_bounds__(256) void k_zcnt(int* __restrict__ cnts) {
    int t = blockIdx.x * 256 + threadIdx.x;
    if (t < NN) cnts[t] = 0;
}

// ---------------- fused edge kernel ----------------
// Per block: stage fp32 filters -> fp16 transposed LDS [cell][ci_hi][o][ci_lo8].
// Per edge (1 lane): geometry (poly tanh), packed atomic, ballot-compaction;
// 16-lane groups compute 16 outputs per valid edge via fdot2 and store fp32 conv slot.
__global__ __launch_bounds__(256) void k_edge(const float* __restrict__ pos,
                                              const int* __restrict__ ei,
                                              const float* __restrict__ feat,
                                              const float* __restrict__ filt,
                                              float* __restrict__ conv,
                                              int* __restrict__ cnts) {
    __shared__ uint4 sf[2048];   // 32 KiB fp16 filters, granule = cell*32 + (ci>>3)*16 + o
    {
        __half* sh = (__half*)sf;
        const float4* f4 = (const float4*)filt;   // 4096 float4, innermost dim is o (16)
        #pragma unroll
        for (int r = 0; r < 16; ++r) {
            int q = r * 256 + threadIdx.x;
            float4 v = f4[q];
            int cell = q >> 6;
            int ci   = (q >> 2) & 15;
            int o0   = (q & 3) << 2;
            int gb   = cell * 32 + (ci >> 3) * 16 + o0;
            int sl   = ci & 7;
            sh[(gb + 0) * 8 + sl] = __float2half(v.x);
            sh[(gb + 1) * 8 + sl] = __float2half(v.y);
            sh[(gb + 2) * 8 + sl] = __float2half(v.z);
            sh[(gb + 3) * 8 + sl] = __float2half(v.w);
        }
    }
    __syncthreads();

    int lane = threadIdx.x & 63;
    int gid  = lane >> 4;        // 16-lane group id within wave (0..3)
    int o    = lane & 15;        // output channel owned in compute phase
    int e = (blockIdx.x * 4 + (threadIdx.x >> 6)) * 64 + lane;   // grid covers EE exactly

    int row = ei[e];
    int col = ei[EE + e];

    float rx = pos[col*3+0] - pos[row*3+0];
    float ry = pos[col*3+1] - pos[row*3+1];
    float rz = pos[col*3+2] - pos[row*3+2];
    float d2 = rx*rx + ry*ry + rz*rz;
    bool valid = d2 < R2C;

    // one packed atomic per edge: +1 total count, +1<<16 valid slot
    int old = atomicAdd(&cnts[row], valid ? 0x10001 : 1);

    float win = 0.f, ad = 0.f, bd = 0.f, cd = 0.f;
    int colidx = 0, rowslot = 0;
    if (valid) {
        float u = 1.0f - d2 * 4.0f;           // 1 - d2/R^2
        win = u * u * u;
        // tanh(x)/x = 1 - u/3 + 2u^2/15 - 17u^3/315 + 62u^4/2835, u=x^2<=0.25 (err<1e-5)
        float s = 1.0f + d2*(-0.33333333f + d2*(0.13333333f + d2*(-0.05396825f + d2*0.02186949f)));
        float gx = (rx * s + 1.0f) * 1.5f;    // c-axis (k)
        float gy = (ry * s + 1.0f) * 1.5f;    // b-axis (j)
        float gz = (rz * s + 1.0f) * 1.5f;    // a-axis (i)
        float af = floorf(gz), bf = floorf(gy), cf = floorf(gx);
        int ia0 = min(max((int)af, 0), 2);    // gc in (0.8, 2.2) -> floor in {0,1,2}
        int jb0 = min(max((int)bf, 0), 2);
        int kc0 = min(max((int)cf, 0), 2);
        ad = gz - af; bd = gy - bf; cd = gx - cf;
        colidx  = col | (ia0 << 20) | (jb0 << 24) | (kc0 << 28);
        int slot = old >> 16;
        rowslot = row | (min(slot, MAXDEG) << 16);   // row < 2^16, slot <= 32
    }

    unsigned long long bal = __ballot(valid);
    int nv = __popcll(bal);
    unsigned long long m0 = bal;
    unsigned long long m1 = m0 & (m0 - 1);
    unsigned long long m2 = m1 & (m1 - 1);
    unsigned long long m3 = m2 & (m2 - 1);

    for (int k = 0; k < nv; k += 4) {
        unsigned long long mg = (gid == 0) ? m0 : (gid == 1) ? m1 : (gid == 2) ? m2 : m3;
        bool active = (k + gid) < nv;
        int src = active ? (int)__builtin_ctzll(mg) : 0;

        float win_s = __shfl(win, src, 64);
        float ad_s  = __shfl(ad,  src, 64);
        float bd_s  = __shfl(bd,  src, 64);
        float cd_s  = __shfl(cd,  src, 64);
        int   ci_s  = __shfl(colidx,  src, 64);
        int   rs_s  = __shfl(rowslot, src, 64);

        m0 = m3 & (m3 - 1);
        m1 = m0 & (m0 - 1);
        m2 = m1 & (m1 - 1);
        m3 = m2 & (m2 - 1);

        if (active) {
            int col_s  = ci_s & 0xFFFFF;
            int ia0 = (ci_s >> 20) & 3, jb0 = (ci_s >> 24) & 3, kc0 = (ci_s >> 28) & 3;
            int row_s  = rs_s & 0xFFFF;
            int slot_s = rs_s >> 16;

            const float4* fb = (const float4*)(feat + (size_t)col_s * 16);
            float4 fa = fb[0], fc = fb[1], fd = fb[2], fe = fb[3];

            float va0 = (1.f - ad_s) * win_s, va1 = ad_s * win_s;
            float vb0 = 1.f - bd_s, vb1 = bd_s;
            float vc0 = 1.f - cd_s, vc1 = cd_s;
            float p00 = va0*vb0, p01 = va0*vb1, p10 = va1*vb0, p11 = va1*vb1;
            float w8[8] = { p00*vc0, p00*vc1, p01*vc0, p01*vc1,
                            p10*vc0, p10*vc1, p11*vc0, p11*vc1 };

            int bi = ((ia0 * 16 + jb0 * 4 + kc0) << 5) + o;
            const int cofs[8] = {0, 32, 128, 160, 512, 544, 640, 672};

            float acc = 0.f;
#if HAS_FDOT2
            h2 ft0 = pk(fa.x, fa.y), ft1 = pk(fa.z, fa.w);
            h2 ft2 = pk(fc.x, fc.y), ft3 = pk(fc.z, fc.w);
            h2 ft4 = pk(fd.x, fd.y), ft5 = pk(fd.z, fd.w);
            h2 ft6 = pk(fe.x, fe.y), ft7 = pk(fe.z, fe.w);
            #pragma unroll
            for (int c = 0; c < 8; ++c) {
                uint4 g0 = sf[bi + cofs[c]];
                uint4 g1 = sf[bi + cofs[c] + 16];
                float d = 0.f;
                d = __builtin_amdgcn_fdot2(as_h2(g0.x), ft0, d, false);
                d = __builtin_amdgcn_fdot2(as_h2(g0.y), ft1, d, false);
                d = __builtin_amdgcn_fdot2(as_h2(g0.z), ft2, d, false);
                d = __builtin_amdgcn_fdot2(as_h2(g0.w), ft3, d, false);
                d = __builtin_amdgcn_fdot2(as_h2(g1.x), ft4, d, false);
                d = __builtin_amdgcn_fdot2(as_h2(g1.y), ft5, d, false);
                d = __builtin_amdgcn_fdot2(as_h2(g1.z), ft6, d, false);
                d = __builtin_amdgcn_fdot2(as_h2(g1.w), ft7, d, false);
                acc = fmaf(w8[c], d, acc);
            }
#else
            float ftf[16] = { fa.x, fa.y, fa.z, fa.w, fc.x, fc.y, fc.z, fc.w,
                              fd.x, fd.y, fd.z, fd.w, fe.x, fe.y, fe.z, fe.w };
            #pragma unroll
            for (int c = 0; c < 8; ++c) {
                uint4 g0 = sf[bi + cofs[c]];
                uint4 g1 = sf[bi + cofs[c] + 16];
                float d = 0.f;
                h2 t;
                t = as_h2(g0.x); d = fmaf((float)t.x, ftf[0],  d); d = fmaf((float)t.y, ftf[1],  d);
                t = as_h2(g0.y); d = fmaf((float)t.x, ftf[2],  d); d = fmaf((float)t.y, ftf[3],  d);
                t = as_h2(g0.z); d = fmaf((float)t.x, ftf[4],  d); d = fmaf((float)t.y, ftf[5],  d);
                t = as_h2(g0.w); d = fmaf((float)t.x, ftf[6],  d); d = fmaf((float)t.y, ftf[7],  d);
                t = as_h2(g1.x); d = fmaf((float)t.x, ftf[8],  d); d = fmaf((float)t.y, ftf[9],  d);
                t = as_h2(g1.y); d = fmaf((float)t.x, ftf[10], d); d = fmaf((float)t.y, ftf[11], d);
                t = as_h2(g1.z); d = fmaf((float)t.x, ftf[12], d); d = fmaf((float)t.y, ftf[13], d);
                t = as_h2(g1.w); d = fmaf((float)t.x, ftf[14], d); d = fmaf((float)t.y, ftf[15], d);
                acc = fmaf(w8[c], d, acc);
            }
#endif
            if (slot_s < MAXDEG)
                conv[((size_t)row_s * MAXDEG + slot_s) * 16 + o] = acc;
        }
    }
}

// ---------------- gather: per-node slot-sum + mean (fp32 slots) ----------------
__global__ __launch_bounds__(256) void k_gather(const float* __restrict__ conv,
                                                const int* __restrict__ cnts,
                                                float* __restrict__ out) {
    int t = blockIdx.x * 256 + threadIdx.x;
    int n = t >> 3;
    int h = t & 7;
    if (n >= NN) return;
    int p   = cnts[n];
    int deg = min(p >> 16, MAXDEG);
    int ca  = p & 0xFFFF;
    float2 acc = make_float2(0.f, 0.f);
    const float2* base = (const float2*)(conv + (size_t)n * MAXDEG * 16) + h;
    for (int s = 0; s < deg; ++s) {
        float2 q = base[(size_t)s * 8];
        acc.x += q.x;
        acc.y += q.y;
    }
    float inv = 1.0f / (float)max(ca, 1);
    *(float2*)(out + (size_t)n * 16 + h * 2) = make_float2(acc.x * inv, acc.y * inv);
}

// ---------------- fallback-path zero (out + counters) ----------------
__global__ __launch_bounds__(256) void k_zero(float* __restrict__ out, int* __restrict__ cnt) {
    int i = blockIdx.x * 256 + threadIdx.x;
    if (i < NN * COUT) out[i] = 0.0f;
    if (i < NN) cnt[i] = 0;
}

// ---------------- geometry helper (fallback path) ----------------
__device__ __forceinline__ bool edge_geom(const float* __restrict__ pos, int row, int col,
                                          float& win,
                                          int ia[2], int jb[2], int kc[2],
                                          float wa[2], float wb[2], float wc[2]) {
    float rx = pos[col*3+0] - pos[row*3+0];
    float ry = pos[col*3+1] - pos[row*3+1];
    float rz = pos[col*3+2] - pos[row*3+2];
    float d2 = rx*rx + ry*ry + rz*rz;
    if (!(d2 < R2C)) return false;
    float u = 1.0f - d2 / R2C;
    win = u * u * u;
    float nr = sqrtf(d2);
    float s  = tanhf(nr) / (nr + 1e-8f);
    float gx = (rx * s + 1.0f) * 1.5f;
    float gy = (ry * s + 1.0f) * 1.5f;
    float gz = (rz * s + 1.0f) * 1.5f;
    float af = floorf(gz), bf = floorf(gy), cf = floorf(gx);
    int ia0 = min(max((int)af, 0), 3);
    int ib0 = min(max((int)bf, 0), 3);
    int ic0 = min(max((int)cf, 0), 3);
    ia[0] = ia0; ia[1] = min(ia0 + 1, 3);
    jb[0] = ib0; jb[1] = min(ib0 + 1, 3);
    kc[0] = ic0; kc[1] = min(ic0 + 1, 3);
    float ad = gz - af, bd = gy - bf, cd = gx - cf;
    wa[0] = 1.0f - ad; wa[1] = ad;
    wb[0] = 1.0f - bd; wb[1] = bd;
    wc[0] = 1.0f - cd; wc[1] = cd;
    return true;
}

// ---------------- fallback: direct edge kernel, filters from global ----------------
__global__ __launch_bounds__(256) void k_edge_direct(const float* __restrict__ pos,
                                                     const float* __restrict__ feat,
                                                     const float* __restrict__ filt,
                                                     const int* __restrict__ ei,
                                                     float* __restrict__ out,
                                                     int* __restrict__ cnt) {
    int e = blockIdx.x * 256 + threadIdx.x;
    if (e >= EE) return;
    int row = ei[e];
    int col = ei[EE + e];
    atomicAdd(&cnt[row], 1);

    float win;
    int ia[2], jb[2], kc[2];
    float wa[2], wb[2], wc[2];
    if (!edge_geom(pos, row, col, win, ia, jb, kc, wa, wb, wc)) return;

    float fv[16];
    const float4* fp = (const float4*)(feat + (size_t)col * 16);
    float4 f0 = fp[0], f1 = fp[1], f2 = fp[2], f3 = fp[3];
    fv[0]=f0.x; fv[1]=f0.y; fv[2]=f0.z; fv[3]=f0.w;
    fv[4]=f1.x; fv[5]=f1.y; fv[6]=f1.z; fv[7]=f1.w;
    fv[8]=f2.x; fv[9]=f2.y; fv[10]=f2.z; fv[11]=f2.w;
    fv[12]=f3.x; fv[13]=f3.y; fv[14]=f3.z; fv[15]=f3.w;

    float4 a0 = make_float4(0.f,0.f,0.f,0.f);
    float4 a1 = a0, a2 = a0, a3 = a0;
    for (int da = 0; da < 2; ++da)
    for (int db = 0; db < 2; ++db)
    for (int dc = 0; dc < 2; ++dc) {
        float w = wa[da] * wb[db] * wc[dc] * win;
        const float* fb = filt + (size_t)(ia[da]*16 + jb[db]*4 + kc[dc]) * 256;
        #pragma unroll
        for (int ci = 0; ci < 16; ++ci) {
            float c = w * fv[ci];
            const float4* r4 = (const float4*)(fb + ci * 16);
            float4 w0 = r4[0], w1 = r4[1], w2 = r4[2], w3 = r4[3];
            a0.x = fmaf(c, w0.x, a0.x); a0.y = fmaf(c, w0.y, a0.y);
            a0.z = fmaf(c, w0.z, a0.z); a0.w = fmaf(c, w0.w, a0.w);
            a1.x = fmaf(c, w1.x, a1.x); a1.y = fmaf(c, w1.y, a1.y);
            a1.z = fmaf(c, w1.z, a1.z); a1.w = fmaf(c, w1.w, a1.w);
            a2.x = fmaf(c, w2.x, a2.x); a2.y = fmaf(c, w2.y, a2.y);
            a2.z = fmaf(c, w2.z, a2.z); a2.w = fmaf(c, w2.w, a2.w);
            a3.x = fmaf(c, w3.x, a3.x); a3.y = fmaf(c, w3.y, a3.y);
            a3.z = fmaf(c, w3.z, a3.z); a3.w = fmaf(c, w3.w, a3.w);
        }
    }
    float* op = out + (size_t)row * 16;
    atomicAdd(op+0,  a0.x); atomicAdd(op+1,  a0.y); atomicAdd(op+2,  a0.z); atomicAdd(op+3,  a0.w);
    atomicAdd(op+4,  a1.x); atomicAdd(op+5,  a1.y); atomicAdd(op+6,  a1.z); atomicAdd(op+7,  a1.w);
    atomicAdd(op+8,  a2.x); atomicAdd(op+9,  a2.y); atomicAdd(op+10, a2.z); atomicAdd(op+11, a2.w);
    atomicAdd(op+12, a3.x); atomicAdd(op+13, a3.y); atomicAdd(op+14, a3.z); atomicAdd(op+15, a3.w);
}

// ---------------- fallback divide ----------------
__global__ __launch_bounds__(256) void k_div(float* __restrict__ out, const int* __restrict__ cnt) {
    int i = blockIdx.x * 256 + threadIdx.x;
    if (i >= NN * COUT) return;
    int c = cnt[i >> 4];
    float denom = (c > 1) ? (float)c : 1.0f;
    out[i] = out[i] / denom;
}

extern "C" void kernel_launch(void* const* d_in, const int* in_sizes, int n_in,
                              void* d_out, int out_size, void* d_ws, size_t ws_size,
                              hipStream_t stream) {
    const float* pos  = (const float*)d_in[0];
    const float* feat = (const float*)d_in[1];
    const float* filt = (const float*)d_in[2];
    const int*   ei   = (const int*)d_in[3];
    float* out = (float*)d_out;

    int*   cnts = (int*)d_ws;
    float* conv = (float*)((char*)d_ws + CONV_OFF);

    size_t need = (size_t)CONV_OFF + (size_t)NN * MAXDEG * 16 * sizeof(float);

    if (ws_size >= need) {
        k_zcnt<<<(NN + 255) / 256, 256, 0, stream>>>(cnts);
        k_edge<<<1250, 256, 0, stream>>>(pos, ei, feat, filt, conv, cnts);
        k_gather<<<(NN * 8 + 255) / 256, 256, 0, stream>>>(conv, cnts, out);
    } else {
        k_zero<<<(NN * COUT + 255) / 256, 256, 0, stream>>>(out, cnts);
        k_edge_direct<<<(EE + 255) / 256, 256, 0, stream>>>(pos, feat, filt, ei, out, cnts);
        k_div<<<(NN * COUT + 255) / 256, 256, 0, stream>>>(out, cnts);
    }
}

// Round 3
// 92.021 us; speedup vs baseline: 1.1740x; 1.0252x over previous
//
#include <hip/hip_runtime.h>
#include <hip/hip_fp16.h>
#include <math.h>

#define NN 20000
#define EE 320000
#define CIN 16
#define COUT 16
#define R2C 0.25f

// workspace layout:
//   cnts : int[NN] @ 0   (total incident edge count per node)
#define WS_NEED 81920

typedef _Float16 h2 __attribute__((ext_vector_type(2)));

#if defined(__has_builtin)
# if __has_builtin(__builtin_amdgcn_fdot2)
#  define HAS_FDOT2 1
# endif
#endif
#ifndef HAS_FDOT2
# define HAS_FDOT2 0
#endif

__device__ __forceinline__ h2 as_h2(unsigned int x) {
    union { unsigned int u; h2 h; } v; v.u = x; return v.h;
}
__device__ __forceinline__ h2 pk(float a, float b) {
    h2 r; r.x = (_Float16)a; r.y = (_Float16)b; return r;
}
__device__ __forceinline__ unsigned int pku(float a, float b) {
    __half2 h = __float22half2_rn(make_float2(a, b));
    return *(unsigned int*)&h;
}

// ---------------- zero out + counters ----------------
__global__ __launch_bounds__(256) void k_zero(float* __restrict__ out, int* __restrict__ cnt) {
    int i = blockIdx.x * 256 + threadIdx.x;
    if (i < NN * COUT) out[i] = 0.0f;
    if (i < NN) cnt[i] = 0;
}

// ---------------- fused edge kernel: geometry + compaction + LDS-filter conv + atomic out ----------------
// 625 blocks x 2 chunks x 256 edges = EE exactly.
// Staging: per-granule gather (coalesced across 16-lane o-groups), one ds_write_b128 per granule.
// LDS layout: granule(16B) = cell*32 + ci_hi*16 + o, holding filt[cell][ci_hi*8 .. +8][o] as 8 halves.
__global__ __launch_bounds__(256) void k_edge(const float* __restrict__ pos,
                                              const int* __restrict__ ei,
                                              const float* __restrict__ feat,
                                              const float* __restrict__ filt,
                                              float* __restrict__ out,
                                              int* __restrict__ cnts) {
    __shared__ uint4 sf[2048];   // 32 KiB fp16 filters
    {
        #pragma unroll
        for (int r = 0; r < 8; ++r) {
            int g = r * 256 + threadIdx.x;                 // granule id == LDS granule index
            const float* src = filt + (g >> 4) * 128 + (g & 15); // cell*256 + ci_hi*128 + o
            float s0 = src[0],  s1 = src[16],  s2 = src[32],  s3 = src[48];
            float s4 = src[64], s5 = src[80],  s6 = src[96],  s7 = src[112];
            uint4 v;
            v.x = pku(s0, s1); v.y = pku(s2, s3);
            v.z = pku(s4, s5); v.w = pku(s6, s7);
            sf[g] = v;
        }
    }
    __syncthreads();

    int lane = threadIdx.x & 63;
    int gid  = lane >> 4;        // 16-lane group id within wave
    int o    = lane & 15;        // output channel owned in compute phase
    int wv   = threadIdx.x >> 6;

    #pragma unroll
    for (int ch = 0; ch < 2; ++ch) {
        int e = blockIdx.x * 512 + ch * 256 + wv * 64 + lane;

        int row = ei[e];
        int col = ei[EE + e];
        atomicAdd(&cnts[row], 1);     // fire-and-forget, mean divisor counts ALL edges

        float rx = pos[col*3+0] - pos[row*3+0];
        float ry = pos[col*3+1] - pos[row*3+1];
        float rz = pos[col*3+2] - pos[row*3+2];
        float d2 = rx*rx + ry*ry + rz*rz;
        bool valid = d2 < R2C;

        float win = 0.f, ad = 0.f, bd = 0.f, cd = 0.f;
        int colidx = 0;
        if (valid) {
            float u = 1.0f - d2 * 4.0f;           // 1 - d2/R^2
            win = u * u * u;
            // tanh(x)/x = 1 - u/3 + 2u^2/15 - 17u^3/315 + 62u^4/2835, u=x^2<=0.25 (err<1e-5)
            float s = 1.0f + d2*(-0.33333333f + d2*(0.13333333f + d2*(-0.05396825f + d2*0.02186949f)));
            float gx = (rx * s + 1.0f) * 1.5f;    // c-axis (k)
            float gy = (ry * s + 1.0f) * 1.5f;    // b-axis (j)
            float gz = (rz * s + 1.0f) * 1.5f;    // a-axis (i)
            float af = floorf(gz), bf = floorf(gy), cf = floorf(gx);
            int ia0 = min(max((int)af, 0), 2);    // gc in (0.8, 2.2) -> floor in {0,1,2}
            int jb0 = min(max((int)bf, 0), 2);
            int kc0 = min(max((int)cf, 0), 2);
            ad = gz - af; bd = gy - bf; cd = gx - cf;
            colidx = col | (ia0 << 20) | (jb0 << 24) | (kc0 << 28);
        }

        unsigned long long bal = __ballot(valid);
        int nv = __popcll(bal);
        unsigned long long m0 = bal;
        unsigned long long m1 = m0 & (m0 - 1);
        unsigned long long m2 = m1 & (m1 - 1);
        unsigned long long m3 = m2 & (m2 - 1);

        for (int k = 0; k < nv; k += 4) {
            unsigned long long mg = (gid == 0) ? m0 : (gid == 1) ? m1 : (gid == 2) ? m2 : m3;
            bool active = (k + gid) < nv;
            int src = active ? (int)__builtin_ctzll(mg) : 0;

            float win_s = __shfl(win, src, 64);
            float ad_s  = __shfl(ad,  src, 64);
            float bd_s  = __shfl(bd,  src, 64);
            float cd_s  = __shfl(cd,  src, 64);
            int   ci_s  = __shfl(colidx, src, 64);
            int   row_s = __shfl(row,    src, 64);

            m0 = m3 & (m3 - 1);
            m1 = m0 & (m0 - 1);
            m2 = m1 & (m1 - 1);
            m3 = m2 & (m2 - 1);

            if (active) {
                int col_s = ci_s & 0xFFFFF;
                int ia0 = (ci_s >> 20) & 3, jb0 = (ci_s >> 24) & 3, kc0 = (ci_s >> 28) & 3;

                const float4* fb = (const float4*)(feat + (size_t)col_s * 16);
                float4 fa = fb[0], fc = fb[1], fd = fb[2], fe = fb[3];

                float va0 = (1.f - ad_s) * win_s, va1 = ad_s * win_s;
                float vb0 = 1.f - bd_s, vb1 = bd_s;
                float vc0 = 1.f - cd_s, vc1 = cd_s;
                float p00 = va0*vb0, p01 = va0*vb1, p10 = va1*vb0, p11 = va1*vb1;
                float w8[8] = { p00*vc0, p00*vc1, p01*vc0, p01*vc1,
                                p10*vc0, p10*vc1, p11*vc0, p11*vc1 };

                int bi = ((ia0 * 16 + jb0 * 4 + kc0) << 5) + o;
                const int cofs[8] = {0, 32, 128, 160, 512, 544, 640, 672};

                float acc = 0.f;
#if HAS_FDOT2
                h2 ft0 = pk(fa.x, fa.y), ft1 = pk(fa.z, fa.w);
                h2 ft2 = pk(fc.x, fc.y), ft3 = pk(fc.z, fc.w);
                h2 ft4 = pk(fd.x, fd.y), ft5 = pk(fd.z, fd.w);
                h2 ft6 = pk(fe.x, fe.y), ft7 = pk(fe.z, fe.w);
                #pragma unroll
                for (int c = 0; c < 8; ++c) {
                    uint4 g0 = sf[bi + cofs[c]];
                    uint4 g1 = sf[bi + cofs[c] + 16];
                    float d = 0.f;
                    d = __builtin_amdgcn_fdot2(as_h2(g0.x), ft0, d, false);
                    d = __builtin_amdgcn_fdot2(as_h2(g0.y), ft1, d, false);
                    d = __builtin_amdgcn_fdot2(as_h2(g0.z), ft2, d, false);
                    d = __builtin_amdgcn_fdot2(as_h2(g0.w), ft3, d, false);
                    d = __builtin_amdgcn_fdot2(as_h2(g1.x), ft4, d, false);
                    d = __builtin_amdgcn_fdot2(as_h2(g1.y), ft5, d, false);
                    d = __builtin_amdgcn_fdot2(as_h2(g1.z), ft6, d, false);
                    d = __builtin_amdgcn_fdot2(as_h2(g1.w), ft7, d, false);
                    acc = fmaf(w8[c], d, acc);
                }
#else
                float ftf[16] = { fa.x, fa.y, fa.z, fa.w, fc.x, fc.y, fc.z, fc.w,
                                  fd.x, fd.y, fd.z, fd.w, fe.x, fe.y, fe.z, fe.w };
                #pragma unroll
                for (int c = 0; c < 8; ++c) {
                    uint4 g0 = sf[bi + cofs[c]];
                    uint4 g1 = sf[bi + cofs[c] + 16];
                    float d = 0.f;
                    h2 t;
                    t = as_h2(g0.x); d = fmaf((float)t.x, ftf[0],  d); d = fmaf((float)t.y, ftf[1],  d);
                    t = as_h2(g0.y); d = fmaf((float)t.x, ftf[2],  d); d = fmaf((float)t.y, ftf[3],  d);
                    t = as_h2(g0.z); d = fmaf((float)t.x, ftf[4],  d); d = fmaf((float)t.y, ftf[5],  d);
                    t = as_h2(g0.w); d = fmaf((float)t.x, ftf[6],  d); d = fmaf((float)t.y, ftf[7],  d);
                    t = as_h2(g1.x); d = fmaf((float)t.x, ftf[8],  d); d = fmaf((float)t.y, ftf[9],  d);
                    t = as_h2(g1.y); d = fmaf((float)t.x, ftf[10], d); d = fmaf((float)t.y, ftf[11], d);
                    t = as_h2(g1.z); d = fmaf((float)t.x, ftf[12], d); d = fmaf((float)t.y, ftf[13], d);
                    t = as_h2(g1.w); d = fmaf((float)t.x, ftf[14], d); d = fmaf((float)t.y, ftf[15], d);
                    acc = fmaf(w8[c], d, acc);
                }
#endif
                atomicAdd(out + (size_t)row_s * 16 + o, acc);
            }
        }
    }
}

// ---------------- divide by all-edge count ----------------
__global__ __launch_bounds__(256) void k_div(float* __restrict__ out, const int* __restrict__ cnt) {
    int i = blockIdx.x * 256 + threadIdx.x;
    if (i >= NN * COUT) return;
    int c = cnt[i >> 4];
    float denom = (c > 1) ? (float)c : 1.0f;
    out[i] = out[i] / denom;
}

// ---------------- geometry helper (fallback path) ----------------
__device__ __forceinline__ bool edge_geom(const float* __restrict__ pos, int row, int col,
                                          float& win,
                                          int ia[2], int jb[2], int kc[2],
                                          float wa[2], float wb[2], float wc[2]) {
    float rx = pos[col*3+0] - pos[row*3+0];
    float ry = pos[col*3+1] - pos[row*3+1];
    float rz = pos[col*3+2] - pos[row*3+2];
    float d2 = rx*rx + ry*ry + rz*rz;
    if (!(d2 < R2C)) return false;
    float u = 1.0f - d2 / R2C;
    win = u * u * u;
    float nr = sqrtf(d2);
    float s  = tanhf(nr) / (nr + 1e-8f);
    float gx = (rx * s + 1.0f) * 1.5f;
    float gy = (ry * s + 1.0f) * 1.5f;
    float gz = (rz * s + 1.0f) * 1.5f;
    float af = floorf(gz), bf = floorf(gy), cf = floorf(gx);
    int ia0 = min(max((int)af, 0), 3);
    int ib0 = min(max((int)bf, 0), 3);
    int ic0 = min(max((int)cf, 0), 3);
    ia[0] = ia0; ia[1] = min(ia0 + 1, 3);
    jb[0] = ib0; jb[1] = min(ib0 + 1, 3);
    kc[0] = ic0; kc[1] = min(ic0 + 1, 3);
    float ad = gz - af, bd = gy - bf, cd = gx - cf;
    wa[0] = 1.0f - ad; wa[1] = ad;
    wb[0] = 1.0f - bd; wb[1] = bd;
    wc[0] = 1.0f - cd; wc[1] = cd;
    return true;
}

// ---------------- fallback: direct edge kernel, filters from global ----------------
__global__ __launch_bounds__(256) void k_edge_direct(const float* __restrict__ pos,
                                                     const float* __restrict__ feat,
                                                     const float* __restrict__ filt,
                                                     const int* __restrict__ ei,
                                                     float* __restrict__ out,
                                                     int* __restrict__ cnt) {
    int e = blockIdx.x * 256 + threadIdx.x;
    if (e >= EE) return;
    int row = ei[e];
    int col = ei[EE + e];
    atomicAdd(&cnt[row], 1);

    float win;
    int ia[2], jb[2], kc[2];
    float wa[2], wb[2], wc[2];
    if (!edge_geom(pos, row, col, win, ia, jb, kc, wa, wb, wc)) return;

    float fv[16];
    const float4* fp = (const float4*)(feat + (size_t)col * 16);
    float4 f0 = fp[0], f1 = fp[1], f2 = fp[2], f3 = fp[3];
    fv[0]=f0.x; fv[1]=f0.y; fv[2]=f0.z; fv[3]=f0.w;
    fv[4]=f1.x; fv[5]=f1.y; fv[6]=f1.z; fv[7]=f1.w;
    fv[8]=f2.x; fv[9]=f2.y; fv[10]=f2.z; fv[11]=f2.w;
    fv[12]=f3.x; fv[13]=f3.y; fv[14]=f3.z; fv[15]=f3.w;

    float4 a0 = make_float4(0.f,0.f,0.f,0.f);
    float4 a1 = a0, a2 = a0, a3 = a0;
    for (int da = 0; da < 2; ++da)
    for (int db = 0; db < 2; ++db)
    for (int dc = 0; dc < 2; ++dc) {
        float w = wa[da] * wb[db] * wc[dc] * win;
        const float* fb = filt + (size_t)(ia[da]*16 + jb[db]*4 + kc[dc]) * 256;
        #pragma unroll
        for (int ci = 0; ci < 16; ++ci) {
            float c = w * fv[ci];
            const float4* r4 = (const float4*)(fb + ci * 16);
            float4 w0 = r4[0], w1 = r4[1], w2 = r4[2], w3 = r4[3];
            a0.x = fmaf(c, w0.x, a0.x); a0.y = fmaf(c, w0.y, a0.y);
            a0.z = fmaf(c, w0.z, a0.z); a0.w = fmaf(c, w0.w, a0.w);
            a1.x = fmaf(c, w1.x, a1.x); a1.y = fmaf(c, w1.y, a1.y);
            a1.z = fmaf(c, w1.z, a1.z); a1.w = fmaf(c, w1.w, a1.w);
            a2.x = fmaf(c, w2.x, a2.x); a2.y = fmaf(c, w2.y, a2.y);
            a2.z = fmaf(c, w2.z, a2.z); a2.w = fmaf(c, w2.w, a2.w);
            a3.x = fmaf(c, w3.x, a3.x); a3.y = fmaf(c, w3.y, a3.y);
            a3.z = fmaf(c, w3.z, a3.z); a3.w = fmaf(c, w3.w, a3.w);
        }
    }
    float* op = out + (size_t)row * 16;
    atomicAdd(op+0,  a0.x); atomicAdd(op+1,  a0.y); atomicAdd(op+2,  a0.z); atomicAdd(op+3,  a0.w);
    atomicAdd(op+4,  a1.x); atomicAdd(op+5,  a1.y); atomicAdd(op+6,  a1.z); atomicAdd(op+7,  a1.w);
    atomicAdd(op+8,  a2.x); atomicAdd(op+9,  a2.y); atomicAdd(op+10, a2.z); atomicAdd(op+11, a2.w);
    atomicAdd(op+12, a3.x); atomicAdd(op+13, a3.y); atomicAdd(op+14, a3.z); atomicAdd(op+15, a3.w);
}

extern "C" void kernel_launch(void* const* d_in, const int* in_sizes, int n_in,
                              void* d_out, int out_size, void* d_ws, size_t ws_size,
                              hipStream_t stream) {
    const float* pos  = (const float*)d_in[0];
    const float* feat = (const float*)d_in[1];
    const float* filt = (const float*)d_in[2];
    const int*   ei   = (const int*)d_in[3];
    float* out = (float*)d_out;

    int* cnts = (int*)d_ws;

    k_zero<<<(NN * COUT + 255) / 256, 256, 0, stream>>>(out, cnts);
    if (ws_size >= WS_NEED) {
        k_edge<<<625, 256, 0, stream>>>(pos, ei, feat, filt, out, cnts);
    } else {
        k_edge_direct<<<(EE + 255) / 256, 256, 0, stream>>>(pos, feat, filt, ei, out, cnts);
    }
    k_div<<<(NN * COUT + 255) / 256, 256, 0, stream>>>(out, cnts);
}